// Round 15
// baseline (174.622 us; speedup 1.0000x reference)
//
#include <hip/hip_runtime.h>

#define BB 4
#define CC 256
#define NN 8192
#define HH 4
#define NCH 32  // n-chunks for KV partial reduction (512 blocks = 2/CU)

typedef unsigned short u16;
typedef __bf16 bf16x8 __attribute__((ext_vector_type(8)));
typedef float f32x4 __attribute__((ext_vector_type(4)));

__device__ __forceinline__ float bf2f(unsigned u) {
  return __uint_as_float(u << 16);
}
__device__ __forceinline__ u16 f2bf(float f) {
  unsigned u = __float_as_uint(f);
  return (u16)((u + 0x7fffu + ((u >> 16) & 1u)) >> 16);
}
__device__ __forceinline__ void bf8_to_f32(uint4 r, float* f) {
  f[0] = __uint_as_float(r.x << 16); f[1] = __uint_as_float(r.x & 0xffff0000u);
  f[2] = __uint_as_float(r.y << 16); f[3] = __uint_as_float(r.y & 0xffff0000u);
  f[4] = __uint_as_float(r.z << 16); f[5] = __uint_as_float(r.z & 0xffff0000u);
  f[6] = __uint_as_float(r.w << 16); f[7] = __uint_as_float(r.w & 0xffff0000u);
}
// async global->LDS, 16B/lane; LDS dest = wave-uniform base + lane*16 (linear only)
__device__ __forceinline__ void gload16(const u16* g, u16* l) {
  __builtin_amdgcn_global_load_lds(
      (const __attribute__((address_space(1))) unsigned int*)g,
      (__attribute__((address_space(3))) unsigned int*)l, 16, 0, 0);
}

// ---------------- fused weight f32 -> bf16 convert (all 6 weights) ----------------
__global__ __launch_bounds__(256) void cvt_all_kernel(
    const float* __restrict__ wq, const float* __restrict__ wk,
    const float* __restrict__ wv, const float* __restrict__ wa,
    const float* __restrict__ w1, const float* __restrict__ w2,
    u16* __restrict__ oq, u16* __restrict__ ok, u16* __restrict__ ov,
    u16* __restrict__ oa, u16* __restrict__ o1, u16* __restrict__ o2) {
  int i = blockIdx.x * 256 + threadIdx.x;  // [0, 655360)
  const float* src;
  u16* dst;
  int off;
  if (i < 65536) { src = wq; dst = oq; off = i; }
  else if (i < 131072) { src = wk; dst = ok; off = i - 65536; }
  else if (i < 196608) { src = wv; dst = ov; off = i - 131072; }
  else if (i < 262144) { src = wa; dst = oa; off = i - 196608; }
  else if (i < 524288) { src = w1; dst = o1; off = i - 262144; }
  else { src = w2; dst = o2; off = i - 524288; }
  dst[off] = f2bf(src[off]);
}

// ---------------- x [B,C,N] f32 -> xt [B,N,C] bf16 (z<4: x1, z>=4: x2) ----------------
__global__ __launch_bounds__(256) void transpose_kernel(const float* __restrict__ x1,
                                                        const float* __restrict__ x2,
                                                        u16* __restrict__ x1t,
                                                        u16* __restrict__ x2t) {
  __shared__ float T[64][65];
  const int bz = blockIdx.z;
  const int b = bz & 3;
  const float* x = (bz < 4) ? x1 : x2;
  u16* xt = (bz < 4) ? x1t : x2t;
  const int c0 = blockIdx.y * 64, n0 = blockIdx.x * 64;
  const float* xp = x + ((size_t)b * CC + c0) * NN + n0;
#pragma unroll
  for (int it = 0; it < 4; ++it) {
    int idx = threadIdx.x + it * 256;
    int r = idx >> 4, seg = idx & 15;
    float4 v = *(const float4*)(xp + (size_t)r * NN + seg * 4);
    T[r][seg * 4 + 0] = v.x; T[r][seg * 4 + 1] = v.y;
    T[r][seg * 4 + 2] = v.z; T[r][seg * 4 + 3] = v.w;
  }
  __syncthreads();
  u16* op = xt + ((size_t)b * NN + n0) * CC + c0;
  const int j = threadIdx.x >> 2, g = threadIdx.x & 3;
#pragma unroll
  for (int i = 0; i < 4; ++i) {
    int c = g * 16 + i * 4;
    uint2 pk;
    pk.x = (unsigned)f2bf(T[c + 0][j]) | ((unsigned)f2bf(T[c + 1][j]) << 16);
    pk.y = (unsigned)f2bf(T[c + 2][j]) | ((unsigned)f2bf(T[c + 3][j]) << 16);
    *(uint2*)(op + (size_t)j * CC + c) = pk;
  }
}

// ---------------- all 4 projections; 128m x 256o, 512 threads; W DIRECT TO REGS ----
// W fragments loaded from global (L2-resident) into registers, issued BEFORE the
// A-staging barrier so the mandatory vmcnt-drain covers their latency (fix for R7).
// mode 0: Q = elu(x1t.Wq+bq)+1      -> Qt   [B*N, C]
// mode 1: K = elu(x2t.Wk+bk)+1      -> K2   [B, C, N]  (transposed)
// mode 2: V = x2t.Wv+bv             -> V2   [B, C, N]  (transposed)
// mode 3: aug = BN(x1t.Wa+ba)       -> augt [B*N, C]
__global__ __launch_bounds__(512, 4) void proj_all_kernel(
    const u16* __restrict__ x1t, const u16* __restrict__ x2t,
    const u16* __restrict__ Wqb, const u16* __restrict__ Wkb,
    const u16* __restrict__ Wvb, const u16* __restrict__ Wab,
    const float* __restrict__ bq, const float* __restrict__ bk,
    const float* __restrict__ bv, const float* __restrict__ ba,
    const float* __restrict__ bng, const float* __restrict__ bnb,
    const float* __restrict__ bnm, const float* __restrict__ bnv,
    u16* __restrict__ Qt, u16* __restrict__ K2, u16* __restrict__ V2,
    u16* __restrict__ augt) {
  // K-loop: As[128][72] only (18.4KB). Epilogue union T: up to 69.6KB.
  __shared__ u16 lds[34816];
  u16* As = lds;
  u16* T = lds;
  const int mode = blockIdx.z;
  const u16* A = (mode == 0 || mode == 3) ? x1t : x2t;
  const u16* W = (mode == 0) ? Wqb : (mode == 1) ? Wkb : (mode == 2) ? Wvb : Wab;
  const float* bias = (mode == 0) ? bq : (mode == 1) ? bk : (mode == 2) ? bv : ba;
  u16* outp = (mode == 0) ? Qt : (mode == 1) ? K2 : (mode == 2) ? V2 : augt;
  const int m0 = blockIdx.x * 128;
  const int tid = threadIdx.x, lane = tid & 63, wave = tid >> 6;
  const int wm = (wave >> 2) * 64, wo = (wave & 3) * 64;
  const int fr = lane & 15, fq = lane >> 4;
  f32x4 acc[4][4] = {};
  for (int kt = 0; kt < 4; ++kt) {
    const int k0 = kt << 6;
    // W fragments: per-lane global loads (L2 hits), issued early
    uint4 wreg[4][2];
#pragma unroll
    for (int oi = 0; oi < 4; ++oi) {
      const u16* wp = W + (size_t)(wo + oi * 16 + fr) * CC + k0;
#pragma unroll
      for (int kk = 0; kk < 2; ++kk)
        wreg[oi][kk] = *(const uint4*)(wp + kk * 32 + fq * 8);
    }
    // A staging (reg->LDS); the pre-barrier vmcnt drain also retires wreg loads
#pragma unroll
    for (int i = 0; i < 2; ++i) {
      int idx = tid + i * 512;
      int r = idx >> 3, s = idx & 7;
      *(uint4*)(&As[r * 72 + s * 8]) = *(const uint4*)(A + (size_t)(m0 + r) * CC + k0 + s * 8);
    }
    __syncthreads();
#pragma unroll
    for (int kk = 0; kk < 2; ++kk) {
      bf16x8 af[4];
#pragma unroll
      for (int mi = 0; mi < 4; ++mi)
        af[mi] = __builtin_bit_cast(bf16x8, *(const uint4*)(&As[(wm + mi * 16 + fr) * 72 + kk * 32 + fq * 8]));
#pragma unroll
      for (int mi = 0; mi < 4; ++mi)
#pragma unroll
        for (int oi = 0; oi < 4; ++oi)
          acc[mi][oi] = __builtin_amdgcn_mfma_f32_16x16x32_bf16(
              af[mi], __builtin_bit_cast(bf16x8, wreg[oi][kk]), acc[mi][oi], 0, 0, 0);
    }
    __syncthreads();
  }
  const int bb_ = m0 >> 13;      // batch (tiles never straddle: 128 | 8192)
  const int nb = m0 & (NN - 1);  // n-offset within batch
  // epilogue math + LDS restage (modes 0/3: T[128][264]; modes 1/2: T[256][136])
#pragma unroll
  for (int oi = 0; oi < 4; ++oi) {
    const int o_loc = wo + oi * 16 + fr;  // [0,256) = output col
    float b0 = bias[o_loc], sc = 1.f, sh = 0.f;
    if (mode == 3) {
      sc = bng[o_loc] * rsqrtf(bnv[o_loc] + 1e-5f);
      sh = (b0 - bnm[o_loc]) * sc + bnb[o_loc];
    }
#pragma unroll
    for (int mi = 0; mi < 4; ++mi) {
      const int mbase = wm + mi * 16 + fq * 4;
      float v[4];
#pragma unroll
      for (int r = 0; r < 4; ++r) {
        float t = acc[mi][oi][r];
        if (mode == 0 || mode == 1) {
          t += b0;
          t = (t > 0.f) ? (t + 1.f) : __expf(t);
        } else if (mode == 2) {
          t += b0;
        } else {
          t = t * sc + sh;
        }
        v[r] = t;
      }
      if (mode == 1 || mode == 2) {
#pragma unroll
        for (int e = 0; e < 2; ++e) {
          unsigned pk = (unsigned)f2bf(v[2 * e]) | ((unsigned)f2bf(v[2 * e + 1]) << 16);
          *(unsigned*)(&T[o_loc * 136 + mbase + 2 * e]) = pk;
        }
      } else {
#pragma unroll
        for (int r = 0; r < 4; ++r) T[(mbase + r) * 264 + o_loc] = f2bf(v[r]);
      }
    }
  }
  __syncthreads();
  // coalesced 16B stores (tile = 64KB -> 4096 chunks, 8 iters @ 512 thr)
  if (mode == 1 || mode == 2) {
#pragma unroll
    for (int i = 0; i < 8; ++i) {
      int idx = tid + i * 512;
      int r = idx >> 4, c = (idx & 15) * 8;  // r = o-row [0,256), c = m-col [0,128)
      *(uint4*)(outp + ((size_t)bb_ * CC + r) * NN + nb + c) = *(const uint4*)(&T[r * 136 + c]);
    }
  } else {
#pragma unroll
    for (int i = 0; i < 8; ++i) {
      int idx = tid + i * 512;
      int r = idx >> 5, c = (idx & 31) * 8;  // r = m-row [0,128), c = o-col [0,256)
      *(uint4*)(outp + (size_t)(m0 + r) * CC + c) = *(const uint4*)(&T[r * 264 + c]);
    }
  }
}

// ---------------- KV partials via MFMA + fused per-chunk Ksum partials (NCH=32) ----------------
__global__ __launch_bounds__(256) void kvpartial_kernel(const u16* __restrict__ K2,
                                                        const u16* __restrict__ V2,
                                                        float* __restrict__ Pkv,
                                                        float* __restrict__ Pks) {
  __shared__ u16 Ks[64 * 64];
  __shared__ u16 Vs[64 * 64];
  const int b = blockIdx.z, h = blockIdx.y, ch = blockIdx.x;
  const int tid = threadIdx.x, lane = tid & 63, w = tid >> 6;
  const int fr = lane & 15, fq = lane >> 4;
  const size_t base = ((size_t)b * CC + h * 64) * NN + (size_t)ch * (NN / NCH);
  f32x4 acc[4] = {};
  const int krow = tid >> 2, kq = tid & 3;  // for Ksum partial: 4 threads/dk-row
  float ksacc = 0.f;
  for (int step = 0; step < (NN / NCH) / 64; ++step) {
#pragma unroll
    for (int i = 0; i < 2; ++i) {
      int idx = tid + i * 256;
      int rr = idx >> 3, ss = idx & 7;
      gload16(K2 + base + (size_t)rr * NN + step * 64 + ss * 8, &Ks[(i * 256 + w * 64) * 8]);
      gload16(V2 + base + (size_t)rr * NN + step * 64 + ss * 8, &Vs[(i * 256 + w * 64) * 8]);
    }
    __syncthreads();
#pragma unroll
    for (int j = 0; j < 16; ++j) ksacc += bf2f(Ks[krow * 64 + kq * 16 + j]);
#pragma unroll
    for (int kk = 0; kk < 2; ++kk) {
      bf16x8 af = __builtin_bit_cast(bf16x8, *(const uint4*)(&Ks[(w * 16 + fr) * 64 + kk * 32 + fq * 8]));
#pragma unroll
      for (int oi = 0; oi < 4; ++oi) {
        bf16x8 bfr = __builtin_bit_cast(bf16x8, *(const uint4*)(&Vs[(oi * 16 + fr) * 64 + kk * 32 + fq * 8]));
        acc[oi] = __builtin_amdgcn_mfma_f32_16x16x32_bf16(af, bfr, acc[oi], 0, 0, 0);
      }
    }
    __syncthreads();
  }
  ksacc += __shfl_xor(ksacc, 1);
  ksacc += __shfl_xor(ksacc, 2);
  if (kq == 0) Pks[((size_t)ch * BB + b) * CC + h * 64 + krow] = ksacc;
  float* o = Pkv + (((size_t)ch * (BB * HH) + b * HH + h) << 12);
#pragma unroll
  for (int oi = 0; oi < 4; ++oi)
#pragma unroll
    for (int r = 0; r < 4; ++r)
      o[(w * 16 + fq * 4 + r) * 64 + oi * 16 + fr] = acc[oi][r];
}

// ---------------- KVT[bh][dv][dk] = bf16( sum_ch Pkv ) ; Ksum[i<1024] = sum_ch Pks ----------------
__global__ __launch_bounds__(256) void kvreduce_kernel(const float* __restrict__ Pkv,
                                                       const float* __restrict__ Pks,
                                                       u16* __restrict__ KVT,
                                                       float* __restrict__ Ksum) {
  int i = blockIdx.x * 256 + threadIdx.x;  // [0, 65536)
  int bh = i >> 12, dk = (i >> 6) & 63, dv = i & 63;
  float s = 0.f;
#pragma unroll
  for (int ch = 0; ch < NCH; ++ch)
    s += Pkv[(((size_t)ch * (BB * HH) + bh) << 12) + (dk << 6) + dv];
  KVT[((size_t)bh << 12) + (dv << 6) + dk] = f2bf(s);
  if (i < BB * CC) {
    float t = 0.f;
#pragma unroll
    for (int ch = 0; ch < NCH; ++ch) t += Pks[ch * (BB * CC) + i];
    Ksum[i] = t;
  }
}

// ---------------- bigmsg: all-heads msg GEMM + fused score/Z + fused LN1 ----------------
__global__ __launch_bounds__(256) void bigmsg_kernel(const u16* __restrict__ Qt,
                                                     const u16* __restrict__ KVT,
                                                     const float* __restrict__ Ksum,
                                                     const float* __restrict__ thrp,
                                                     const float* __restrict__ g1,
                                                     const float* __restrict__ b1,
                                                     u16* __restrict__ msgN) {
  // phase A: As[64][264] (Q) | Ws[4][64][72] (KVT).  phase B: Ml[64][272] (msg, overlaps As)
  __shared__ u16 lds[64 * 264 + 4 * 64 * 72];
  __shared__ float Zs[64 * 4];
  u16* As = lds;
  u16* Ws = lds + 64 * 264;
  u16* Ml = lds;
  const int m0 = blockIdx.x * 64;  // per-batch row
  const int b = blockIdx.z;
  const int tid = threadIdx.x, lane = tid & 63, w = tid >> 6;
  const int fr = lane & 15, fq = lane >> 4;
  const u16* Ap = Qt + ((size_t)b * NN + m0) * CC;
#pragma unroll
  for (int i = 0; i < 8; ++i) {
    int idx = tid + i * 256;
    int rr = idx >> 5, ss = idx & 31;
    *(uint4*)(&As[rr * 264 + ss * 8]) = *(const uint4*)(Ap + (size_t)rr * CC + ss * 8);
  }
  const u16* Wp = KVT + ((size_t)(b * HH) << 12);
#pragma unroll
  for (int i = 0; i < 8; ++i) {
    int idx = tid + i * 256;
    int h = idx >> 9, rr = (idx >> 3) & 63, ss = idx & 7;
    *(uint4*)(&Ws[(h * 64 + rr) * 72 + ss * 8]) = *(const uint4*)(Wp + ((size_t)h << 12) + rr * 64 + ss * 8);
  }
  __syncthreads();
  {
    const int row = tid >> 2, h = tid & 3;
    const float* ks = Ksum + b * CC + h * 64;
    float za = 0.f;
#pragma unroll
    for (int j8 = 0; j8 < 8; ++j8) {
      uint4 raw = *(const uint4*)(&As[row * 264 + h * 64 + j8 * 8]);
      float f[8];
      bf8_to_f32(raw, f);
#pragma unroll
      for (int j = 0; j < 8; ++j) za += f[j] * ks[j8 * 8 + j];
    }
    const float thrv = thrp[0];
    Zs[row * 4 + h] = 1.f / (((za > thrv) ? za : 0.f) + 1e-6f);
  }
  f32x4 acc[4][4] = {};
#pragma unroll
  for (int kk = 0; kk < 2; ++kk) {
    bf16x8 af[4], bfr[4];
#pragma unroll
    for (int mi = 0; mi < 4; ++mi)
      af[mi] = __builtin_bit_cast(bf16x8, *(const uint4*)(&As[(mi * 16 + fr) * 264 + w * 64 + kk * 32 + fq * 8]));
#pragma unroll
    for (int oi = 0; oi < 4; ++oi)
      bfr[oi] = __builtin_bit_cast(bf16x8, *(const uint4*)(&Ws[(w * 64 + oi * 16 + fr) * 72 + kk * 32 + fq * 8]));
#pragma unroll
    for (int mi = 0; mi < 4; ++mi)
#pragma unroll
      for (int oi = 0; oi < 4; ++oi)
        acc[mi][oi] = __builtin_amdgcn_mfma_f32_16x16x32_bf16(af[mi], bfr[oi], acc[mi][oi], 0, 0, 0);
  }
  __syncthreads();
#pragma unroll
  for (int oi = 0; oi < 4; ++oi) {
    const int col = w * 64 + oi * 16 + fr;
#pragma unroll
    for (int mi = 0; mi < 4; ++mi) {
#pragma unroll
      for (int r = 0; r < 4; ++r) {
        const int row = mi * 16 + fq * 4 + r;
        Ml[row * 272 + col] = f2bf(acc[mi][oi][r] * Zs[row * 4 + w]);
      }
    }
  }
  __syncthreads();
  {
    const int row = tid >> 2, q = tid & 3;
    const u16* mrow = &Ml[row * 272 + q * 64];
    float s1 = 0.f, s2 = 0.f;
#pragma unroll
    for (int j8 = 0; j8 < 8; ++j8) {
      uint4 raw = *(const uint4*)(mrow + j8 * 8);
      float f[8];
      bf8_to_f32(raw, f);
#pragma unroll
      for (int j = 0; j < 8; ++j) {
        s1 += f[j];
        s2 += f[j] * f[j];
      }
    }
    s1 += __shfl_xor(s1, 1); s2 += __shfl_xor(s2, 1);
    s1 += __shfl_xor(s1, 2); s2 += __shfl_xor(s2, 2);
    const float mean = s1 * (1.f / CC);
    const float var = s2 * (1.f / CC) - mean * mean;
    const float rs = rsqrtf(var + 1e-5f);
    u16* orow = msgN + ((size_t)b * NN + m0 + row) * CC + q * 64;
#pragma unroll
    for (int j8 = 0; j8 < 8; ++j8) {
      uint4 raw = *(const uint4*)(mrow + j8 * 8);
      float f[8];
      bf8_to_f32(raw, f);
      const int cb = q * 64 + j8 * 8;
      unsigned pk[4];
#pragma unroll
      for (int e = 0; e < 4; ++e) {
        float lo = (f[2 * e] - mean) * rs * g1[cb + 2 * e] + b1[cb + 2 * e];
        float hi = (f[2 * e + 1] - mean) * rs * g1[cb + 2 * e + 1] + b1[cb + 2 * e + 1];
        pk[e] = (unsigned)f2bf(lo) | ((unsigned)f2bf(hi) << 16);
      }
      *(uint4*)(orow + j8 * 8) = make_uint4(pk[0], pk[1], pk[2], pk[3]);
    }
  }
}

// ---------------- MLP1: h1 = relu([x1t | msgN] @ W1^T); 128m x 256o, 512 threads (R11) ----------------
__global__ __launch_bounds__(512, 4) void mlp1_kernel(const u16* __restrict__ A1,
                                                      const u16* __restrict__ A2,
                                                      const u16* __restrict__ W,
                                                      u16* __restrict__ outp) {
  __shared__ u16 lds[34816];  // As[128][72]|Ws[256][72] loop; T[128][264] epilogue
  u16* As = lds;
  u16* Ws = lds + 128 * 72;
  u16* T = lds;
  const int m0 = blockIdx.x * 128, o0 = blockIdx.y * 256;
  const int tid = threadIdx.x, lane = tid & 63, wave = tid >> 6;
  const int wm = (wave >> 2) * 64, wo = (wave & 3) * 64;
  const int fr = lane & 15, fq = lane >> 4;
  f32x4 acc[4][4] = {};
  for (int kt = 0; kt < 8; ++kt) {
    const int k0 = kt << 6;
    const u16* Ap = (k0 < 256) ? (A1 + k0) : (A2 + (k0 - 256));
#pragma unroll
    for (int i = 0; i < 2; ++i) {
      int idx = tid + i * 512;
      int r = idx >> 3, s = idx & 7;
      *(uint4*)(&As[r * 72 + s * 8]) = *(const uint4*)(Ap + (size_t)(m0 + r) * CC + s * 8);
    }
#pragma unroll
    for (int i = 0; i < 4; ++i) {
      int idx = tid + i * 512;
      int r = idx >> 3, s = idx & 7;  // r in [0,256)
      *(uint4*)(&Ws[r * 72 + s * 8]) = *(const uint4*)(W + (size_t)(o0 + r) * 512 + k0 + s * 8);
    }
    __syncthreads();
#pragma unroll
    for (int kk = 0; kk < 2; ++kk) {
      bf16x8 af[4], bfr[4];
#pragma unroll
      for (int mi = 0; mi < 4; ++mi)
        af[mi] = __builtin_bit_cast(bf16x8, *(const uint4*)(&As[(wm + mi * 16 + fr) * 72 + kk * 32 + fq * 8]));
#pragma unroll
      for (int oi = 0; oi < 4; ++oi)
        bfr[oi] = __builtin_bit_cast(bf16x8, *(const uint4*)(&Ws[(wo + oi * 16 + fr) * 72 + kk * 32 + fq * 8]));
#pragma unroll
      for (int mi = 0; mi < 4; ++mi)
#pragma unroll
        for (int oi = 0; oi < 4; ++oi)
          acc[mi][oi] = __builtin_amdgcn_mfma_f32_16x16x32_bf16(af[mi], bfr[oi], acc[mi][oi], 0, 0, 0);
    }
    __syncthreads();
  }
#pragma unroll
  for (int oi = 0; oi < 4; ++oi) {
    const int o_loc = wo + oi * 16 + fr;
#pragma unroll
    for (int mi = 0; mi < 4; ++mi) {
      const int mbase = wm + mi * 16 + fq * 4;
#pragma unroll
      for (int r = 0; r < 4; ++r)
        T[(mbase + r) * 264 + o_loc] = f2bf(fmaxf(acc[mi][oi][r], 0.f));
    }
  }
  __syncthreads();
#pragma unroll
  for (int i = 0; i < 8; ++i) {
    int idx = tid + i * 512;
    int r = idx >> 5, c = (idx & 31) * 8;
    *(uint4*)(outp + (size_t)(m0 + r) * 512 + o0 + c) = *(const uint4*)(&T[r * 264 + c]);
  }
}

// ---------------- MLP2 GEMM: mlp2b = h1 @ W2^T  (R9/R11-proven 256-thread 128x128 form) ----------------
__global__ __launch_bounds__(256) void mlp2_kernel(const u16* __restrict__ h1,
                                                   const u16* __restrict__ W,
                                                   u16* __restrict__ outp) {
  __shared__ u16 lds[2 * 128 * 72];  // As|Ws during loop; T[128][132] epilogue (union)
  u16* As = lds;
  u16* Ws = lds + 128 * 72;
  u16* T = lds;
  const int m0 = blockIdx.x * 128, o0 = blockIdx.y * 128;
  const int tid = threadIdx.x, lane = tid & 63, wave = tid >> 6;
  const int wm = (wave >> 1) * 64, wo = (wave & 1) * 64;
  const int fr = lane & 15, fq = lane >> 4;
  f32x4 acc[4][4] = {};
  for (int kt = 0; kt < 8; ++kt) {
    const int k0 = kt << 6;
#pragma unroll
    for (int i = 0; i < 4; ++i) {
      int idx = tid + i * 256;
      int r = idx >> 3, s = idx & 7;
      *(uint4*)(&As[r * 72 + s * 8]) = *(const uint4*)(h1 + (size_t)(m0 + r) * 512 + k0 + s * 8);
      *(uint4*)(&Ws[r * 72 + s * 8]) = *(const uint4*)(W + (size_t)(o0 + r) * 512 + k0 + s * 8);
    }
    __syncthreads();
#pragma unroll
    for (int kk = 0; kk < 2; ++kk) {
      bf16x8 af[4], bfr[4];
#pragma unroll
      for (int mi = 0; mi < 4; ++mi)
        af[mi] = __builtin_bit_cast(bf16x8, *(const uint4*)(&As[(wm + mi * 16 + fr) * 72 + kk * 32 + fq * 8]));
#pragma unroll
      for (int oi = 0; oi < 4; ++oi)
        bfr[oi] = __builtin_bit_cast(bf16x8, *(const uint4*)(&Ws[(wo + oi * 16 + fr) * 72 + kk * 32 + fq * 8]));
#pragma unroll
      for (int mi = 0; mi < 4; ++mi)
#pragma unroll
        for (int oi = 0; oi < 4; ++oi)
          acc[mi][oi] = __builtin_amdgcn_mfma_f32_16x16x32_bf16(af[mi], bfr[oi], acc[mi][oi], 0, 0, 0);
    }
    __syncthreads();
  }
#pragma unroll
  for (int oi = 0; oi < 4; ++oi) {
    const int o_loc = wo + oi * 16 + fr;
#pragma unroll
    for (int mi = 0; mi < 4; ++mi) {
      const int mbase = wm + mi * 16 + fq * 4;
#pragma unroll
      for (int r = 0; r < 4; ++r)
        T[(mbase + r) * 132 + o_loc] = f2bf(acc[mi][oi][r]);
    }
  }
  __syncthreads();
#pragma unroll
  for (int i = 0; i < 8; ++i) {
    int idx = tid + i * 256;
    int r = idx >> 4, c = (idx & 15) * 8;
    *(uint4*)(outp + (size_t)(m0 + r) * CC + o0 + c) = *(const uint4*)(&T[r * 132 + c]);
  }
}

// ---------------- lnaddT: LN2 + aug + transpose + x1-add -> out f32 [B,C,N] ----------------
__global__ __launch_bounds__(256) void lnaddT_kernel(const u16* __restrict__ mlp2b,
                                                     const u16* __restrict__ augt,
                                                     const float* __restrict__ x1,
                                                     const float* __restrict__ g2,
                                                     const float* __restrict__ b2,
                                                     float* __restrict__ outp) {
  __shared__ u16 T[256 * 67];  // [c][n] bf16
  const int b = blockIdx.y, n0 = blockIdx.x * 64;
  const int tid = threadIdx.x;
  {
    const int r = tid >> 2, q = tid & 3;
    const size_t rowoff = ((size_t)b * NN + n0 + r) * CC + q * 64;
    uint4 raw[8];
    float s1 = 0.f, s2 = 0.f;
#pragma unroll
    for (int j8 = 0; j8 < 8; ++j8) {
      raw[j8] = *(const uint4*)(mlp2b + rowoff + j8 * 8);
      float f[8];
      bf8_to_f32(raw[j8], f);
#pragma unroll
      for (int j = 0; j < 8; ++j) {
        s1 += f[j];
        s2 += f[j] * f[j];
      }
    }
    s1 += __shfl_xor(s1, 1); s2 += __shfl_xor(s2, 1);
    s1 += __shfl_xor(s1, 2); s2 += __shfl_xor(s2, 2);
    const float mean = s1 * (1.f / CC);
    const float var = s2 * (1.f / CC) - mean * mean;
    const float rs = rsqrtf(var + 1e-5f);
#pragma unroll
    for (int j8 = 0; j8 < 8; ++j8) {
      uint4 ar = *(const uint4*)(augt + rowoff + j8 * 8);
      float f[8], af[8];
      bf8_to_f32(raw[j8], f);
      bf8_to_f32(ar, af);
      const int cb = q * 64 + j8 * 8;
#pragma unroll
      for (int e = 0; e < 8; ++e) {
        float v = (f[e] - mean) * rs * g2[cb + e] + b2[cb + e] + af[e];
        T[(cb + e) * 67 + r] = f2bf(v);
      }
    }
  }
  __syncthreads();
#pragma unroll
  for (int i = 0; i < 64; ++i) {
    int idx = tid + i * 256;  // 0..16383
    int c = idx >> 6, n = idx & 63;
    size_t off = ((size_t)b * CC + c) * NN + n0 + n;
    outp[off] = bf2f(T[c * 67 + n]) + x1[off];
  }
}

extern "C" void kernel_launch(void* const* d_in, const int* in_sizes, int n_in,
                              void* d_out, int out_size, void* d_ws, size_t ws_size,
                              hipStream_t stream) {
  (void)in_sizes; (void)n_in; (void)out_size; (void)ws_size;
  const float* x1 = (const float*)d_in[0];
  const float* x2 = (const float*)d_in[1];
  const float* Wq = (const float*)d_in[2];
  const float* bq = (const float*)d_in[3];
  const float* Wk = (const float*)d_in[4];
  const float* bk = (const float*)d_in[5];
  const float* Wv = (const float*)d_in[6];
  const float* bv = (const float*)d_in[7];
  const float* thr = (const float*)d_in[8];
  const float* W1 = (const float*)d_in[9];
  const float* W2 = (const float*)d_in[10];
  const float* g1 = (const float*)d_in[11];
  const float* b1 = (const float*)d_in[12];
  const float* g2 = (const float*)d_in[13];
  const float* b2 = (const float*)d_in[14];
  const float* Wa = (const float*)d_in[15];
  const float* ba = (const float*)d_in[16];
  const float* bng = (const float*)d_in[17];
  const float* bnb = (const float*)d_in[18];
  const float* bnm = (const float*)d_in[19];
  const float* bnv = (const float*)d_in[20];
  float* out = (float*)d_out;

  // Slot lifetime map (SZ = 16.78 MB each; strictly stream-ordered):
  //  slot 0: x1t                  (live until mlp1)
  //  slot 1: x2t                  (dead after proj_all)
  //  slot 2: Qt  -> h1(lo half)
  //  slot 3: K2  -> h1(hi half)
  //  slot 4: V2  -> msgN -> mlp2b
  //  slot 5: augt                 (live until lnaddT)
  //  slot 6: Pkv (8 MB)
  char* ws = (char*)d_ws;
  constexpr size_t SZ = (size_t)BB * NN * CC * sizeof(u16);  // 16.78 MB
  u16* x1t = (u16*)(ws);
  u16* x2t = (u16*)(ws + SZ);
  u16* Qt = (u16*)(ws + 2 * SZ);
  u16* K2 = (u16*)(ws + 3 * SZ);  // [B,C,N]
  u16* V2 = (u16*)(ws + 4 * SZ);  // [B,C,N]
  u16* augt = (u16*)(ws + 5 * SZ);
  float* Pkv = (float*)(ws + 6 * SZ);  // NCH*16*4096*4 = 8 MB
  u16* h1 = Qt;     // slots 2+3 contiguous (32768 x 512 bf16)
  u16* msgN = V2;   // slot 4 after V2 dead
  u16* mlp2b = V2;  // slot 4 after msgN consumed by mlp1
  char* tail = ws + 7 * SZ;
  float* Ksum = (float*)tail;                       // 4 KB
  u16* KVT = (u16*)(tail + 4096);                   // 128 KB
  float* Pks = (float*)(tail + 4096 + 131072);      // NCH*BB*CC*4 = 128 KB
  u16* Wqb = (u16*)(tail + 4096 + 131072 + 131072);
  u16* Wkb = Wqb + CC * CC;
  u16* Wvb = Wkb + CC * CC;
  u16* Wab = Wvb + CC * CC;
  u16* W1b = Wab + CC * CC;
  u16* W2b = W1b + 512 * 512;

  cvt_all_kernel<<<dim3(2560), 256, 0, stream>>>(Wq, Wk, Wv, Wa, W1, W2,
                                                 Wqb, Wkb, Wvb, Wab, W1b, W2b);
  transpose_kernel<<<dim3(NN / 64, CC / 64, 2 * BB), 256, 0, stream>>>(x1, x2, x1t, x2t);
  // 512-thread blocks, 128m x 256o; W direct-to-registers (issued ahead of A barrier)
  proj_all_kernel<<<dim3(256, 1, 4), 512, 0, stream>>>(
      x1t, x2t, Wqb, Wkb, Wvb, Wab, bq, bk, bv, ba, bng, bnb, bnm, bnv,
      Qt, K2, V2, augt);
  kvpartial_kernel<<<dim3(NCH, HH, BB), 256, 0, stream>>>(K2, V2, Pkv, Pks);
  kvreduce_kernel<<<dim3(256), 256, 0, stream>>>(Pkv, Pks, KVT, Ksum);
  bigmsg_kernel<<<dim3(NN / 64, 1, BB), 256, 0, stream>>>(Qt, KVT, Ksum, thr, g1, b1, msgN);
  mlp1_kernel<<<dim3(256, 2), 512, 0, stream>>>(x1t, msgN, W1b, h1);
  mlp2_kernel<<<dim3(256, 2), 256, 0, stream>>>(h1, W2b, mlp2b);
  lnaddT_kernel<<<dim3(NN / 64, BB), 256, 0, stream>>>(mlp2b, augt, x1, g2, b2, out);
}

// Round 16
// 162.284 us; speedup vs baseline: 1.0760x; 1.0760x over previous
//
#include <hip/hip_runtime.h>

#define BB 4
#define CC 256
#define NN 8192
#define HH 4
#define NCH 32  // n-chunks for KV partial reduction (512 blocks = 2/CU)

typedef unsigned short u16;
typedef __bf16 bf16x8 __attribute__((ext_vector_type(8)));
typedef float f32x4 __attribute__((ext_vector_type(4)));

__device__ __forceinline__ float bf2f(unsigned u) {
  return __uint_as_float(u << 16);
}
__device__ __forceinline__ u16 f2bf(float f) {
  unsigned u = __float_as_uint(f);
  return (u16)((u + 0x7fffu + ((u >> 16) & 1u)) >> 16);
}
__device__ __forceinline__ void bf8_to_f32(uint4 r, float* f) {
  f[0] = __uint_as_float(r.x << 16); f[1] = __uint_as_float(r.x & 0xffff0000u);
  f[2] = __uint_as_float(r.y << 16); f[3] = __uint_as_float(r.y & 0xffff0000u);
  f[4] = __uint_as_float(r.z << 16); f[5] = __uint_as_float(r.z & 0xffff0000u);
  f[6] = __uint_as_float(r.w << 16); f[7] = __uint_as_float(r.w & 0xffff0000u);
}
// async global->LDS, 16B/lane; LDS dest = wave-uniform base + lane*16 (linear only)
__device__ __forceinline__ void gload16(const u16* g, u16* l) {
  __builtin_amdgcn_global_load_lds(
      (const __attribute__((address_space(1))) unsigned int*)g,
      (__attribute__((address_space(3))) unsigned int*)l, 16, 0, 0);
}

// ---------------- fused weight f32 -> bf16 convert (all 6 weights) ----------------
__global__ __launch_bounds__(256) void cvt_all_kernel(
    const float* __restrict__ wq, const float* __restrict__ wk,
    const float* __restrict__ wv, const float* __restrict__ wa,
    const float* __restrict__ w1, const float* __restrict__ w2,
    u16* __restrict__ oq, u16* __restrict__ ok, u16* __restrict__ ov,
    u16* __restrict__ oa, u16* __restrict__ o1, u16* __restrict__ o2) {
  int i = blockIdx.x * 256 + threadIdx.x;  // [0, 655360)
  const float* src;
  u16* dst;
  int off;
  if (i < 65536) { src = wq; dst = oq; off = i; }
  else if (i < 131072) { src = wk; dst = ok; off = i - 65536; }
  else if (i < 196608) { src = wv; dst = ov; off = i - 131072; }
  else if (i < 262144) { src = wa; dst = oa; off = i - 196608; }
  else if (i < 524288) { src = w1; dst = o1; off = i - 262144; }
  else { src = w2; dst = o2; off = i - 524288; }
  dst[off] = f2bf(src[off]);
}

// ---------------- x [B,C,N] f32 -> xt [B,N,C] bf16 (z<4: x1, z>=4: x2) ----------------
__global__ __launch_bounds__(256) void transpose_kernel(const float* __restrict__ x1,
                                                        const float* __restrict__ x2,
                                                        u16* __restrict__ x1t,
                                                        u16* __restrict__ x2t) {
  __shared__ float T[64][65];
  const int bz = blockIdx.z;
  const int b = bz & 3;
  const float* x = (bz < 4) ? x1 : x2;
  u16* xt = (bz < 4) ? x1t : x2t;
  const int c0 = blockIdx.y * 64, n0 = blockIdx.x * 64;
  const float* xp = x + ((size_t)b * CC + c0) * NN + n0;
#pragma unroll
  for (int it = 0; it < 4; ++it) {
    int idx = threadIdx.x + it * 256;
    int r = idx >> 4, seg = idx & 15;
    float4 v = *(const float4*)(xp + (size_t)r * NN + seg * 4);
    T[r][seg * 4 + 0] = v.x; T[r][seg * 4 + 1] = v.y;
    T[r][seg * 4 + 2] = v.z; T[r][seg * 4 + 3] = v.w;
  }
  __syncthreads();
  u16* op = xt + ((size_t)b * NN + n0) * CC + c0;
  const int j = threadIdx.x >> 2, g = threadIdx.x & 3;
#pragma unroll
  for (int i = 0; i < 4; ++i) {
    int c = g * 16 + i * 4;
    uint2 pk;
    pk.x = (unsigned)f2bf(T[c + 0][j]) | ((unsigned)f2bf(T[c + 1][j]) << 16);
    pk.y = (unsigned)f2bf(T[c + 2][j]) | ((unsigned)f2bf(T[c + 3][j]) << 16);
    *(uint2*)(op + (size_t)j * CC + c) = pk;
  }
}

// ---------------- all 4 projections; 128m x 256o per block, 512 THREADS (R11 form) ----
// mode 0: Q = elu(x1t.Wq+bq)+1      -> Qt   [B*N, C]
// mode 1: K = elu(x2t.Wk+bk)+1      -> K2   [B, C, N]  (transposed)
// mode 2: V = x2t.Wv+bv             -> V2   [B, C, N]  (transposed)
// mode 3: aug = BN(x1t.Wa+ba)       -> augt [B*N, C]
__global__ __launch_bounds__(512, 4) void proj_all_kernel(
    const u16* __restrict__ x1t, const u16* __restrict__ x2t,
    const u16* __restrict__ Wqb, const u16* __restrict__ Wkb,
    const u16* __restrict__ Wvb, const u16* __restrict__ Wab,
    const float* __restrict__ bq, const float* __restrict__ bk,
    const float* __restrict__ bv, const float* __restrict__ ba,
    const float* __restrict__ bng, const float* __restrict__ bnb,
    const float* __restrict__ bnm, const float* __restrict__ bnv,
    u16* __restrict__ Qt, u16* __restrict__ K2, u16* __restrict__ V2,
    u16* __restrict__ augt) {
  // K-loop: As[128][72] | Ws[256][72] = 55.3KB. Epilogue union T: 68KB. 2 blocks/CU.
  __shared__ u16 lds[34816];
  u16* As = lds;
  u16* Ws = lds + 128 * 72;
  u16* T = lds;
  const int mode = blockIdx.z;
  const u16* A = (mode == 0 || mode == 3) ? x1t : x2t;
  const u16* W = (mode == 0) ? Wqb : (mode == 1) ? Wkb : (mode == 2) ? Wvb : Wab;
  const float* bias = (mode == 0) ? bq : (mode == 1) ? bk : (mode == 2) ? bv : ba;
  u16* outp = (mode == 0) ? Qt : (mode == 1) ? K2 : (mode == 2) ? V2 : augt;
  const int m0 = blockIdx.x * 128;
  const int tid = threadIdx.x, lane = tid & 63, wave = tid >> 6;
  const int wm = (wave >> 2) * 64, wo = (wave & 3) * 64;
  const int fr = lane & 15, fq = lane >> 4;
  f32x4 acc[4][4] = {};
  for (int kt = 0; kt < 4; ++kt) {
    const int k0 = kt << 6;
#pragma unroll
    for (int i = 0; i < 2; ++i) {
      int idx = tid + i * 512;
      int r = idx >> 3, s = idx & 7;
      *(uint4*)(&As[r * 72 + s * 8]) = *(const uint4*)(A + (size_t)(m0 + r) * CC + k0 + s * 8);
    }
#pragma unroll
    for (int i = 0; i < 4; ++i) {
      int idx = tid + i * 512;
      int r = idx >> 3, s = idx & 7;  // r in [0,256): full W k-slice
      *(uint4*)(&Ws[r * 72 + s * 8]) = *(const uint4*)(W + (size_t)r * CC + k0 + s * 8);
    }
    __syncthreads();
#pragma unroll
    for (int kk = 0; kk < 2; ++kk) {
      bf16x8 af[4], bfr[4];
#pragma unroll
      for (int mi = 0; mi < 4; ++mi)
        af[mi] = __builtin_bit_cast(bf16x8, *(const uint4*)(&As[(wm + mi * 16 + fr) * 72 + kk * 32 + fq * 8]));
#pragma unroll
      for (int oi = 0; oi < 4; ++oi)
        bfr[oi] = __builtin_bit_cast(bf16x8, *(const uint4*)(&Ws[(wo + oi * 16 + fr) * 72 + kk * 32 + fq * 8]));
#pragma unroll
      for (int mi = 0; mi < 4; ++mi)
#pragma unroll
        for (int oi = 0; oi < 4; ++oi)
          acc[mi][oi] = __builtin_amdgcn_mfma_f32_16x16x32_bf16(af[mi], bfr[oi], acc[mi][oi], 0, 0, 0);
    }
    __syncthreads();
  }
  const int bb_ = m0 >> 13;      // batch (tiles never straddle: 128 | 8192)
  const int nb = m0 & (NN - 1);  // n-offset within batch
  // epilogue math + LDS restage (modes 0/3: T[128][264]; modes 1/2: T[256][136])
#pragma unroll
  for (int oi = 0; oi < 4; ++oi) {
    const int o_loc = wo + oi * 16 + fr;  // [0,256) = output col
    float b0 = bias[o_loc], sc = 1.f, sh = 0.f;
    if (mode == 3) {
      sc = bng[o_loc] * rsqrtf(bnv[o_loc] + 1e-5f);
      sh = (b0 - bnm[o_loc]) * sc + bnb[o_loc];
    }
#pragma unroll
    for (int mi = 0; mi < 4; ++mi) {
      const int mbase = wm + mi * 16 + fq * 4;
      float v[4];
#pragma unroll
      for (int r = 0; r < 4; ++r) {
        float t = acc[mi][oi][r];
        if (mode == 0 || mode == 1) {
          t += b0;
          t = (t > 0.f) ? (t + 1.f) : __expf(t);
        } else if (mode == 2) {
          t += b0;
        } else {
          t = t * sc + sh;
        }
        v[r] = t;
      }
      if (mode == 1 || mode == 2) {
#pragma unroll
        for (int e = 0; e < 2; ++e) {
          unsigned pk = (unsigned)f2bf(v[2 * e]) | ((unsigned)f2bf(v[2 * e + 1]) << 16);
          *(unsigned*)(&T[o_loc * 136 + mbase + 2 * e]) = pk;
        }
      } else {
#pragma unroll
        for (int r = 0; r < 4; ++r) T[(mbase + r) * 264 + o_loc] = f2bf(v[r]);
      }
    }
  }
  __syncthreads();
  // coalesced 16B stores (tile = 64KB -> 4096 chunks, 8 iters @ 512 thr)
  if (mode == 1 || mode == 2) {
#pragma unroll
    for (int i = 0; i < 8; ++i) {
      int idx = tid + i * 512;
      int r = idx >> 4, c = (idx & 15) * 8;  // r = o-row [0,256), c = m-col [0,128)
      *(uint4*)(outp + ((size_t)bb_ * CC + r) * NN + nb + c) = *(const uint4*)(&T[r * 136 + c]);
    }
  } else {
#pragma unroll
    for (int i = 0; i < 8; ++i) {
      int idx = tid + i * 512;
      int r = idx >> 5, c = (idx & 31) * 8;  // r = m-row [0,128), c = o-col [0,256)
      *(uint4*)(outp + (size_t)(m0 + r) * CC + c) = *(const uint4*)(&T[r * 264 + c]);
    }
  }
}

// ---------------- KV partials via MFMA + fused per-chunk Ksum partials (NCH=32) ----------------
__global__ __launch_bounds__(256) void kvpartial_kernel(const u16* __restrict__ K2,
                                                        const u16* __restrict__ V2,
                                                        float* __restrict__ Pkv,
                                                        float* __restrict__ Pks) {
  __shared__ u16 Ks[64 * 64];
  __shared__ u16 Vs[64 * 64];
  const int b = blockIdx.z, h = blockIdx.y, ch = blockIdx.x;
  const int tid = threadIdx.x, lane = tid & 63, w = tid >> 6;
  const int fr = lane & 15, fq = lane >> 4;
  const size_t base = ((size_t)b * CC + h * 64) * NN + (size_t)ch * (NN / NCH);
  f32x4 acc[4] = {};
  const int krow = tid >> 2, kq = tid & 3;  // for Ksum partial: 4 threads/dk-row
  float ksacc = 0.f;
  for (int step = 0; step < (NN / NCH) / 64; ++step) {
#pragma unroll
    for (int i = 0; i < 2; ++i) {
      int idx = tid + i * 256;
      int rr = idx >> 3, ss = idx & 7;
      gload16(K2 + base + (size_t)rr * NN + step * 64 + ss * 8, &Ks[(i * 256 + w * 64) * 8]);
      gload16(V2 + base + (size_t)rr * NN + step * 64 + ss * 8, &Vs[(i * 256 + w * 64) * 8]);
    }
    __syncthreads();
#pragma unroll
    for (int j = 0; j < 16; ++j) ksacc += bf2f(Ks[krow * 64 + kq * 16 + j]);
#pragma unroll
    for (int kk = 0; kk < 2; ++kk) {
      bf16x8 af = __builtin_bit_cast(bf16x8, *(const uint4*)(&Ks[(w * 16 + fr) * 64 + kk * 32 + fq * 8]));
#pragma unroll
      for (int oi = 0; oi < 4; ++oi) {
        bf16x8 bfr = __builtin_bit_cast(bf16x8, *(const uint4*)(&Vs[(oi * 16 + fr) * 64 + kk * 32 + fq * 8]));
        acc[oi] = __builtin_amdgcn_mfma_f32_16x16x32_bf16(af, bfr, acc[oi], 0, 0, 0);
      }
    }
    __syncthreads();
  }
  ksacc += __shfl_xor(ksacc, 1);
  ksacc += __shfl_xor(ksacc, 2);
  if (kq == 0) Pks[((size_t)ch * BB + b) * CC + h * 64 + krow] = ksacc;
  float* o = Pkv + (((size_t)ch * (BB * HH) + b * HH + h) << 12);
#pragma unroll
  for (int oi = 0; oi < 4; ++oi)
#pragma unroll
    for (int r = 0; r < 4; ++r)
      o[(w * 16 + fq * 4 + r) * 64 + oi * 16 + fr] = acc[oi][r];
}

// ---------------- KVT[bh][dv][dk] = bf16( sum_ch Pkv ) ; Ksum[i<1024] = sum_ch Pks ----------------
__global__ __launch_bounds__(256) void kvreduce_kernel(const float* __restrict__ Pkv,
                                                       const float* __restrict__ Pks,
                                                       u16* __restrict__ KVT,
                                                       float* __restrict__ Ksum) {
  int i = blockIdx.x * 256 + threadIdx.x;  // [0, 65536)
  int bh = i >> 12, dk = (i >> 6) & 63, dv = i & 63;
  float s = 0.f;
#pragma unroll
  for (int ch = 0; ch < NCH; ++ch)
    s += Pkv[(((size_t)ch * (BB * HH) + bh) << 12) + (dk << 6) + dv];
  KVT[((size_t)bh << 12) + (dv << 6) + dk] = f2bf(s);
  if (i < BB * CC) {
    float t = 0.f;
#pragma unroll
    for (int ch = 0; ch < NCH; ++ch) t += Pks[ch * (BB * CC) + i];
    Ksum[i] = t;
  }
}

// ---------------- bigmsg: all-heads msg GEMM + fused score/Z + fused LN1 ----------------
__global__ __launch_bounds__(256) void bigmsg_kernel(const u16* __restrict__ Qt,
                                                     const u16* __restrict__ KVT,
                                                     const float* __restrict__ Ksum,
                                                     const float* __restrict__ thrp,
                                                     const float* __restrict__ g1,
                                                     const float* __restrict__ b1,
                                                     u16* __restrict__ msgN) {
  // phase A: As[64][264] (Q) | Ws[4][64][72] (KVT).  phase B: Ml[64][272] (msg, overlaps As)
  __shared__ u16 lds[64 * 264 + 4 * 64 * 72];
  __shared__ float Zs[64 * 4];
  u16* As = lds;
  u16* Ws = lds + 64 * 264;
  u16* Ml = lds;
  const int m0 = blockIdx.x * 64;  // per-batch row
  const int b = blockIdx.z;
  const int tid = threadIdx.x, lane = tid & 63, w = tid >> 6;
  const int fr = lane & 15, fq = lane >> 4;
  const u16* Ap = Qt + ((size_t)b * NN + m0) * CC;
#pragma unroll
  for (int i = 0; i < 8; ++i) {
    int idx = tid + i * 256;
    int rr = idx >> 5, ss = idx & 31;
    *(uint4*)(&As[rr * 264 + ss * 8]) = *(const uint4*)(Ap + (size_t)rr * CC + ss * 8);
  }
  const u16* Wp = KVT + ((size_t)(b * HH) << 12);
#pragma unroll
  for (int i = 0; i < 8; ++i) {
    int idx = tid + i * 256;
    int h = idx >> 9, rr = (idx >> 3) & 63, ss = idx & 7;
    *(uint4*)(&Ws[(h * 64 + rr) * 72 + ss * 8]) = *(const uint4*)(Wp + ((size_t)h << 12) + rr * 64 + ss * 8);
  }
  __syncthreads();
  {
    const int row = tid >> 2, h = tid & 3;
    const float* ks = Ksum + b * CC + h * 64;
    float za = 0.f;
#pragma unroll
    for (int j8 = 0; j8 < 8; ++j8) {
      uint4 raw = *(const uint4*)(&As[row * 264 + h * 64 + j8 * 8]);
      float f[8];
      bf8_to_f32(raw, f);
#pragma unroll
      for (int j = 0; j < 8; ++j) za += f[j] * ks[j8 * 8 + j];
    }
    const float thrv = thrp[0];
    Zs[row * 4 + h] = 1.f / (((za > thrv) ? za : 0.f) + 1e-6f);
  }
  f32x4 acc[4][4] = {};
#pragma unroll
  for (int kk = 0; kk < 2; ++kk) {
    bf16x8 af[4], bfr[4];
#pragma unroll
    for (int mi = 0; mi < 4; ++mi)
      af[mi] = __builtin_bit_cast(bf16x8, *(const uint4*)(&As[(mi * 16 + fr) * 264 + w * 64 + kk * 32 + fq * 8]));
#pragma unroll
    for (int oi = 0; oi < 4; ++oi)
      bfr[oi] = __builtin_bit_cast(bf16x8, *(const uint4*)(&Ws[(w * 64 + oi * 16 + fr) * 72 + kk * 32 + fq * 8]));
#pragma unroll
    for (int mi = 0; mi < 4; ++mi)
#pragma unroll
      for (int oi = 0; oi < 4; ++oi)
        acc[mi][oi] = __builtin_amdgcn_mfma_f32_16x16x32_bf16(af[mi], bfr[oi], acc[mi][oi], 0, 0, 0);
  }
  __syncthreads();
#pragma unroll
  for (int oi = 0; oi < 4; ++oi) {
    const int col = w * 64 + oi * 16 + fr;
#pragma unroll
    for (int mi = 0; mi < 4; ++mi) {
#pragma unroll
      for (int r = 0; r < 4; ++r) {
        const int row = mi * 16 + fq * 4 + r;
        Ml[row * 272 + col] = f2bf(acc[mi][oi][r] * Zs[row * 4 + w]);
      }
    }
  }
  __syncthreads();
  {
    const int row = tid >> 2, q = tid & 3;
    const u16* mrow = &Ml[row * 272 + q * 64];
    float s1 = 0.f, s2 = 0.f;
#pragma unroll
    for (int j8 = 0; j8 < 8; ++j8) {
      uint4 raw = *(const uint4*)(mrow + j8 * 8);
      float f[8];
      bf8_to_f32(raw, f);
#pragma unroll
      for (int j = 0; j < 8; ++j) {
        s1 += f[j];
        s2 += f[j] * f[j];
      }
    }
    s1 += __shfl_xor(s1, 1); s2 += __shfl_xor(s2, 1);
    s1 += __shfl_xor(s1, 2); s2 += __shfl_xor(s2, 2);
    const float mean = s1 * (1.f / CC);
    const float var = s2 * (1.f / CC) - mean * mean;
    const float rs = rsqrtf(var + 1e-5f);
    u16* orow = msgN + ((size_t)b * NN + m0 + row) * CC + q * 64;
#pragma unroll
    for (int j8 = 0; j8 < 8; ++j8) {
      uint4 raw = *(const uint4*)(mrow + j8 * 8);
      float f[8];
      bf8_to_f32(raw, f);
      const int cb = q * 64 + j8 * 8;
      unsigned pk[4];
#pragma unroll
      for (int e = 0; e < 4; ++e) {
        float lo = (f[2 * e] - mean) * rs * g1[cb + 2 * e] + b1[cb + 2 * e];
        float hi = (f[2 * e + 1] - mean) * rs * g1[cb + 2 * e + 1] + b1[cb + 2 * e + 1];
        pk[e] = (unsigned)f2bf(lo) | ((unsigned)f2bf(hi) << 16);
      }
      *(uint4*)(orow + j8 * 8) = make_uint4(pk[0], pk[1], pk[2], pk[3]);
    }
  }
}

// ---------------- MLP1: h1 = relu([x1t | msgN] @ W1^T); 128m x 256o, 512 threads (R11) ----------------
__global__ __launch_bounds__(512, 4) void mlp1_kernel(const u16* __restrict__ A1,
                                                      const u16* __restrict__ A2,
                                                      const u16* __restrict__ W,
                                                      u16* __restrict__ outp) {
  __shared__ u16 lds[34816];  // As[128][72]|Ws[256][72] loop; T[128][264] epilogue
  u16* As = lds;
  u16* Ws = lds + 128 * 72;
  u16* T = lds;
  const int m0 = blockIdx.x * 128, o0 = blockIdx.y * 256;
  const int tid = threadIdx.x, lane = tid & 63, wave = tid >> 6;
  const int wm = (wave >> 2) * 64, wo = (wave & 3) * 64;
  const int fr = lane & 15, fq = lane >> 4;
  f32x4 acc[4][4] = {};
  for (int kt = 0; kt < 8; ++kt) {
    const int k0 = kt << 6;
    const u16* Ap = (k0 < 256) ? (A1 + k0) : (A2 + (k0 - 256));
#pragma unroll
    for (int i = 0; i < 2; ++i) {
      int idx = tid + i * 512;
      int r = idx >> 3, s = idx & 7;
      *(uint4*)(&As[r * 72 + s * 8]) = *(const uint4*)(Ap + (size_t)(m0 + r) * CC + s * 8);
    }
#pragma unroll
    for (int i = 0; i < 4; ++i) {
      int idx = tid + i * 512;
      int r = idx >> 3, s = idx & 7;  // r in [0,256)
      *(uint4*)(&Ws[r * 72 + s * 8]) = *(const uint4*)(W + (size_t)(o0 + r) * 512 + k0 + s * 8);
    }
    __syncthreads();
#pragma unroll
    for (int kk = 0; kk < 2; ++kk) {
      bf16x8 af[4], bfr[4];
#pragma unroll
      for (int mi = 0; mi < 4; ++mi)
        af[mi] = __builtin_bit_cast(bf16x8, *(const uint4*)(&As[(wm + mi * 16 + fr) * 72 + kk * 32 + fq * 8]));
#pragma unroll
      for (int oi = 0; oi < 4; ++oi)
        bfr[oi] = __builtin_bit_cast(bf16x8, *(const uint4*)(&Ws[(wo + oi * 16 + fr) * 72 + kk * 32 + fq * 8]));
#pragma unroll
      for (int mi = 0; mi < 4; ++mi)
#pragma unroll
        for (int oi = 0; oi < 4; ++oi)
          acc[mi][oi] = __builtin_amdgcn_mfma_f32_16x16x32_bf16(af[mi], bfr[oi], acc[mi][oi], 0, 0, 0);
    }
    __syncthreads();
  }
#pragma unroll
  for (int oi = 0; oi < 4; ++oi) {
    const int o_loc = wo + oi * 16 + fr;
#pragma unroll
    for (int mi = 0; mi < 4; ++mi) {
      const int mbase = wm + mi * 16 + fq * 4;
#pragma unroll
      for (int r = 0; r < 4; ++r)
        T[(mbase + r) * 264 + o_loc] = f2bf(fmaxf(acc[mi][oi][r], 0.f));
    }
  }
  __syncthreads();
#pragma unroll
  for (int i = 0; i < 8; ++i) {
    int idx = tid + i * 512;
    int r = idx >> 5, c = (idx & 31) * 8;
    *(uint4*)(outp + (size_t)(m0 + r) * 512 + o0 + c) = *(const uint4*)(&T[r * 264 + c]);
  }
}

// ---------------- MLP2 GEMM: mlp2b = h1 @ W2^T  (R9/R11-proven 256-thread 128x128 form) ----------------
__global__ __launch_bounds__(256) void mlp2_kernel(const u16* __restrict__ h1,
                                                   const u16* __restrict__ W,
                                                   u16* __restrict__ outp) {
  __shared__ u16 lds[2 * 128 * 72];  // As|Ws during loop; T[128][132] epilogue (union)
  u16* As = lds;
  u16* Ws = lds + 128 * 72;
  u16* T = lds;
  const int m0 = blockIdx.x * 128, o0 = blockIdx.y * 128;
  const int tid = threadIdx.x, lane = tid & 63, wave = tid >> 6;
  const int wm = (wave >> 1) * 64, wo = (wave & 1) * 64;
  const int fr = lane & 15, fq = lane >> 4;
  f32x4 acc[4][4] = {};
  for (int kt = 0; kt < 8; ++kt) {
    const int k0 = kt << 6;
#pragma unroll
    for (int i = 0; i < 4; ++i) {
      int idx = tid + i * 256;
      int r = idx >> 3, s = idx & 7;
      *(uint4*)(&As[r * 72 + s * 8]) = *(const uint4*)(h1 + (size_t)(m0 + r) * 512 + k0 + s * 8);
      *(uint4*)(&Ws[r * 72 + s * 8]) = *(const uint4*)(W + (size_t)(o0 + r) * 512 + k0 + s * 8);
    }
    __syncthreads();
#pragma unroll
    for (int kk = 0; kk < 2; ++kk) {
      bf16x8 af[4], bfr[4];
#pragma unroll
      for (int mi = 0; mi < 4; ++mi)
        af[mi] = __builtin_bit_cast(bf16x8, *(const uint4*)(&As[(wm + mi * 16 + fr) * 72 + kk * 32 + fq * 8]));
#pragma unroll
      for (int oi = 0; oi < 4; ++oi)
        bfr[oi] = __builtin_bit_cast(bf16x8, *(const uint4*)(&Ws[(wo + oi * 16 + fr) * 72 + kk * 32 + fq * 8]));
#pragma unroll
      for (int mi = 0; mi < 4; ++mi)
#pragma unroll
        for (int oi = 0; oi < 4; ++oi)
          acc[mi][oi] = __builtin_amdgcn_mfma_f32_16x16x32_bf16(af[mi], bfr[oi], acc[mi][oi], 0, 0, 0);
    }
    __syncthreads();
  }
#pragma unroll
  for (int oi = 0; oi < 4; ++oi) {
    const int o_loc = wo + oi * 16 + fr;
#pragma unroll
    for (int mi = 0; mi < 4; ++mi) {
      const int mbase = wm + mi * 16 + fq * 4;
#pragma unroll
      for (int r = 0; r < 4; ++r)
        T[(mbase + r) * 132 + o_loc] = f2bf(acc[mi][oi][r]);
    }
  }
  __syncthreads();
#pragma unroll
  for (int i = 0; i < 8; ++i) {
    int idx = tid + i * 256;
    int r = idx >> 4, c = (idx & 15) * 8;
    *(uint4*)(outp + (size_t)(m0 + r) * CC + o0 + c) = *(const uint4*)(&T[r * 132 + c]);
  }
}

// ---------------- lnaddT: LN2 + aug + transpose + x1-add -> out f32 [B,C,N] ----------------
__global__ __launch_bounds__(256) void lnaddT_kernel(const u16* __restrict__ mlp2b,
                                                     const u16* __restrict__ augt,
                                                     const float* __restrict__ x1,
                                                     const float* __restrict__ g2,
                                                     const float* __restrict__ b2,
                                                     float* __restrict__ outp) {
  __shared__ u16 T[256 * 67];  // [c][n] bf16
  const int b = blockIdx.y, n0 = blockIdx.x * 64;
  const int tid = threadIdx.x;
  {
    const int r = tid >> 2, q = tid & 3;
    const size_t rowoff = ((size_t)b * NN + n0 + r) * CC + q * 64;
    uint4 raw[8];
    float s1 = 0.f, s2 = 0.f;
#pragma unroll
    for (int j8 = 0; j8 < 8; ++j8) {
      raw[j8] = *(const uint4*)(mlp2b + rowoff + j8 * 8);
      float f[8];
      bf8_to_f32(raw[j8], f);
#pragma unroll
      for (int j = 0; j < 8; ++j) {
        s1 += f[j];
        s2 += f[j] * f[j];
      }
    }
    s1 += __shfl_xor(s1, 1); s2 += __shfl_xor(s2, 1);
    s1 += __shfl_xor(s1, 2); s2 += __shfl_xor(s2, 2);
    const float mean = s1 * (1.f / CC);
    const float var = s2 * (1.f / CC) - mean * mean;
    const float rs = rsqrtf(var + 1e-5f);
#pragma unroll
    for (int j8 = 0; j8 < 8; ++j8) {
      uint4 ar = *(const uint4*)(augt + rowoff + j8 * 8);
      float f[8], af[8];
      bf8_to_f32(raw[j8], f);
      bf8_to_f32(ar, af);
      const int cb = q * 64 + j8 * 8;
#pragma unroll
      for (int e = 0; e < 8; ++e) {
        float v = (f[e] - mean) * rs * g2[cb + e] + b2[cb + e] + af[e];
        T[(cb + e) * 67 + r] = f2bf(v);
      }
    }
  }
  __syncthreads();
#pragma unroll
  for (int i = 0; i < 64; ++i) {
    int idx = tid + i * 256;  // 0..16383
    int c = idx >> 6, n = idx & 63;
    size_t off = ((size_t)b * CC + c) * NN + n0 + n;
    outp[off] = bf2f(T[c * 67 + n]) + x1[off];
  }
}

extern "C" void kernel_launch(void* const* d_in, const int* in_sizes, int n_in,
                              void* d_out, int out_size, void* d_ws, size_t ws_size,
                              hipStream_t stream) {
  (void)in_sizes; (void)n_in; (void)out_size; (void)ws_size;
  const float* x1 = (const float*)d_in[0];
  const float* x2 = (const float*)d_in[1];
  const float* Wq = (const float*)d_in[2];
  const float* bq = (const float*)d_in[3];
  const float* Wk = (const float*)d_in[4];
  const float* bk = (const float*)d_in[5];
  const float* Wv = (const float*)d_in[6];
  const float* bv = (const float*)d_in[7];
  const float* thr = (const float*)d_in[8];
  const float* W1 = (const float*)d_in[9];
  const float* W2 = (const float*)d_in[10];
  const float* g1 = (const float*)d_in[11];
  const float* b1 = (const float*)d_in[12];
  const float* g2 = (const float*)d_in[13];
  const float* b2 = (const float*)d_in[14];
  const float* Wa = (const float*)d_in[15];
  const float* ba = (const float*)d_in[16];
  const float* bng = (const float*)d_in[17];
  const float* bnb = (const float*)d_in[18];
  const float* bnm = (const float*)d_in[19];
  const float* bnv = (const float*)d_in[20];
  float* out = (float*)d_out;

  // Slot lifetime map (SZ = 16.78 MB each; strictly stream-ordered):
  //  slot 0: x1t                  (live until mlp1)
  //  slot 1: x2t                  (dead after proj_all)
  //  slot 2: Qt  -> h1(lo half)
  //  slot 3: K2  -> h1(hi half)
  //  slot 4: V2  -> msgN -> mlp2b
  //  slot 5: augt                 (live until lnaddT)
  //  slot 6: Pkv (8 MB)
  char* ws = (char*)d_ws;
  constexpr size_t SZ = (size_t)BB * NN * CC * sizeof(u16);  // 16.78 MB
  u16* x1t = (u16*)(ws);
  u16* x2t = (u16*)(ws + SZ);
  u16* Qt = (u16*)(ws + 2 * SZ);
  u16* K2 = (u16*)(ws + 3 * SZ);  // [B,C,N]
  u16* V2 = (u16*)(ws + 4 * SZ);  // [B,C,N]
  u16* augt = (u16*)(ws + 5 * SZ);
  float* Pkv = (float*)(ws + 6 * SZ);  // NCH*16*4096*4 = 8 MB
  u16* h1 = Qt;     // slots 2+3 contiguous (32768 x 512 bf16)
  u16* msgN = V2;   // slot 4 after V2 dead
  u16* mlp2b = V2;  // slot 4 after msgN consumed by mlp1
  char* tail = ws + 7 * SZ;
  float* Ksum = (float*)tail;                       // 4 KB
  u16* KVT = (u16*)(tail + 4096);                   // 128 KB
  float* Pks = (float*)(tail + 4096 + 131072);      // NCH*BB*CC*4 = 128 KB
  u16* Wqb = (u16*)(tail + 4096 + 131072 + 131072);
  u16* Wkb = Wqb + CC * CC;
  u16* Wvb = Wkb + CC * CC;
  u16* Wab = Wvb + CC * CC;
  u16* W1b = Wab + CC * CC;
  u16* W2b = W1b + 512 * 512;

  cvt_all_kernel<<<dim3(2560), 256, 0, stream>>>(Wq, Wk, Wv, Wa, W1, W2,
                                                 Wqb, Wkb, Wvb, Wab, W1b, W2b);
  transpose_kernel<<<dim3(NN / 64, CC / 64, 2 * BB), 256, 0, stream>>>(x1, x2, x1t, x2t);
  // R11 form: 512-thread blocks, 128m x 256o, A+W LDS-staged
  proj_all_kernel<<<dim3(256, 1, 4), 512, 0, stream>>>(
      x1t, x2t, Wqb, Wkb, Wvb, Wab, bq, bk, bv, ba, bng, bnb, bnm, bnv,
      Qt, K2, V2, augt);
  kvpartial_kernel<<<dim3(NCH, HH, BB), 256, 0, stream>>>(K2, V2, Pkv, Pks);
  kvreduce_kernel<<<dim3(256), 256, 0, stream>>>(Pkv, Pks, KVT, Ksum);
  bigmsg_kernel<<<dim3(NN / 64, 1, BB), 256, 0, stream>>>(Qt, KVT, Ksum, thr, g1, b1, msgN);
  mlp1_kernel<<<dim3(256, 2), 512, 0, stream>>>(x1t, msgN, W1b, h1);
  mlp2_kernel<<<dim3(256, 2), 256, 0, stream>>>(h1, W2b, mlp2b);
  lnaddT_kernel<<<dim3(NN / 64, BB), 256, 0, stream>>>(mlp2b, augt, x1, g2, b2, out);
}